// Round 7
// baseline (438.676 us; speedup 1.0000x reference)
//
#include <hip/hip_runtime.h>
#include <hip/hip_bf16.h>

// ---------------------------------------------------------------------------
// EncoderGNN: 3-layer GINE encoder, N=50000, E=800000, H=128.
// Round 7: (a) atomic counters (deg / fill_ptr) padded to 1 per 64B line ->
// kills cross-XCD line ping-pong on count/fill atomics; (b) agg uses 2 waves
// per node (split edge range + LDS combine) -> halves the serial gather chain.
// Everything else as round 6 (scalarized agg loop, MFMA MLP, 16B edge recs).
// ---------------------------------------------------------------------------

#define HDIM 128
#define CTR_S 16   // counter stride in ints (64B)

typedef unsigned int uint32;
typedef unsigned short ushort16;
typedef __attribute__((ext_vector_type(8))) short short8;
typedef __attribute__((ext_vector_type(4))) float f32x4;
typedef __attribute__((ext_vector_type(2))) float f32x2;

__device__ __forceinline__ ushort16 f2bf(float f) {
    uint32 u = __float_as_uint(f);
    u += 0x7fff + ((u >> 16) & 1);      // round-to-nearest-even
    return (ushort16)(u >> 16);
}
__device__ __forceinline__ float bflo(uint32 g) { return __uint_as_float(g << 16); }
__device__ __forceinline__ float bfhi(uint32 g) { return __uint_as_float(g & 0xffff0000u); }

// ---------------- CSR build (padded counters) ----------------
__global__ void count_kernel(const int* __restrict__ dstIdx, int* __restrict__ deg_p, int E) {
    int e = blockIdx.x * blockDim.x + threadIdx.x;
    if (e < E) atomicAdd(&deg_p[(size_t)dstIdx[e] * CTR_S], 1);
}

__global__ __launch_bounds__(256) void partial_kernel(const int* __restrict__ deg_p,
                                                      int* __restrict__ partials, int N) {
    __shared__ int red[256];
    int i = blockIdx.x * 256 + threadIdx.x;
    red[threadIdx.x] = (i < N) ? deg_p[(size_t)i * CTR_S] : 0;
    __syncthreads();
#pragma unroll
    for (int off = 128; off > 0; off >>= 1) {
        if (threadIdx.x < off) red[threadIdx.x] += red[threadIdx.x + off];
        __syncthreads();
    }
    if (threadIdx.x == 0) partials[blockIdx.x] = red[0];
}

__global__ __launch_bounds__(256) void scan_partials_kernel(const int* __restrict__ partials,
                                                            int* __restrict__ offsets,
                                                            int nb, int* __restrict__ row_ptr,
                                                            int N, int E) {
    __shared__ int buf[256];
    int tid = threadIdx.x;
    buf[tid] = (tid < nb) ? partials[tid] : 0;
    __syncthreads();
#pragma unroll
    for (int off = 1; off < 256; off <<= 1) {
        int v = (tid >= off) ? buf[tid - off] : 0;
        __syncthreads();
        buf[tid] += v;
        __syncthreads();
    }
    if (tid < nb) offsets[tid] = buf[tid] - partials[tid];   // exclusive
    if (tid == 0) row_ptr[N] = E;
}

__global__ __launch_bounds__(256) void scatter_scan_kernel(const int* __restrict__ deg_p,
                                                           const int* __restrict__ offsets,
                                                           int* __restrict__ row_ptr,
                                                           int* __restrict__ fill_p, int N) {
    __shared__ int buf[256];
    int tid = threadIdx.x;
    int i = blockIdx.x * 256 + tid;
    int v = (i < N) ? deg_p[(size_t)i * CTR_S] : 0;
    buf[tid] = v;
    __syncthreads();
#pragma unroll
    for (int off = 1; off < 256; off <<= 1) {
        int t = (tid >= off) ? buf[tid - off] : 0;
        __syncthreads();
        buf[tid] += t;
        __syncthreads();
    }
    if (i < N) {
        int excl = buf[tid] - v + offsets[blockIdx.x];
        row_ptr[i] = excl;
        fill_p[(size_t)i * CTR_S] = excl;
    }
}

// one 16B record per edge: {src, ea01(bf16x2), ea23(bf16x2), 0}
__global__ void fill_kernel(const int* __restrict__ srcIdx, const int* __restrict__ dstIdx,
                            const float* __restrict__ edge_attr,
                            int* __restrict__ fill_p, int4* __restrict__ adj, int E) {
    int e = blockIdx.x * blockDim.x + threadIdx.x;
    if (e < E) {
        int d = dstIdx[e];
        int pos = atomicAdd(&fill_p[(size_t)d * CTR_S], 1);
        float4 ea = *(const float4*)(edge_attr + (size_t)e * 4);
        int4 rec;
        rec.x = srcIdx[e];
        rec.y = (int)(((uint32)f2bf(ea.y) << 16) | (uint32)f2bf(ea.x));
        rec.z = (int)(((uint32)f2bf(ea.w) << 16) | (uint32)f2bf(ea.z));
        rec.w = 0;
        adj[pos] = rec;
    }
}

// ---------------- weight prep: bf16 + transpose (once per call) ----------------
__global__ void prep_weights(const float* __restrict__ W1, const float* __restrict__ W2,
                             ushort16* __restrict__ Wb1t, ushort16* __restrict__ Wb2t, int total) {
    int idx = blockIdx.x * 256 + threadIdx.x;
    if (idx >= total) return;
    int l = idx >> 14;
    int rem = idx & 16383;
    int n = rem >> 7, k = rem & 127;
    size_t src = (size_t)l * 16384 + (size_t)k * 128 + n;
    size_t dst = (size_t)l * 16384 + (size_t)n * 128 + k;
    Wb1t[dst] = f2bf(W1[src]);
    Wb2t[dst] = f2bf(W2[src]);
}

// ---------------- node embedding (writes bf16 h) ----------------
__global__ void embed_kernel(const int* __restrict__ x_type, const float* __restrict__ x_feat,
                             const float* __restrict__ type_embed, const float* __restrict__ featW,
                             const float* __restrict__ featb, ushort16* __restrict__ h, int N) {
    int idx = blockIdx.x * 256 + threadIdx.x;
    int n = idx >> 7, c = idx & 127;
    if (n >= N) return;
    int t = x_type[n];
    float acc = type_embed[(size_t)t * HDIM + c] + featb[c];
#pragma unroll
    for (int k = 0; k < 7; ++k)
        acc = fmaf(x_feat[(size_t)n * 7 + k], featW[(size_t)k * HDIM + c], acc);
    h[(size_t)n * HDIM + c] = f2bf(acc);
}

// ---------------- aggregation: 2 waves per node, scalarized edge loop ----------------
// Block = 256 thd = 2 node-slots x 2 waves. Each wave takes half the edge
// range (contiguous, so adj stays SMEM-loadable); partials combined via LDS.
__global__ __launch_bounds__(256) void agg_kernel(
        const uint32* __restrict__ hq,       // [N][64] packed bf16x2
        const int* __restrict__ row_ptr,
        const int4* __restrict__ adj,        // 16B records (uniform per wave)
        const float* __restrict__ edgeW, const float* __restrict__ edgeb,
        const float* __restrict__ eps, int l, uint32* __restrict__ zq, int N) {
    __shared__ float2 red[2][64];
    const int tid = threadIdx.x;
    const int nodeSlot = tid >> 7, w = (tid >> 6) & 1, lane = tid & 63;
    const int node = blockIdx.x * 2 + nodeSlot;
    const bool active = node < N;

    const int c0 = 2 * lane;
    const f32x2 w0 = {edgeW[c0],       edgeW[c0 + 1]};
    const f32x2 w1 = {edgeW[128 + c0], edgeW[128 + c0 + 1]};
    const f32x2 w2 = {edgeW[256 + c0], edgeW[256 + c0 + 1]};
    const f32x2 w3 = {edgeW[384 + c0], edgeW[384 + c0 + 1]};
    const f32x2 eb = {edgeb[c0],       edgeb[c0 + 1]};

    int beg = 0, end = 0;
    if (active) {
        beg = __builtin_amdgcn_readfirstlane(row_ptr[node]);
        end = __builtin_amdgcn_readfirstlane(row_ptr[node + 1]);
    }
    const int mid = beg + ((end - beg + 1) >> 1);
    const int lo = w ? mid : beg;
    const int hi = w ? end : mid;

    // self-term loaded early by wave 0
    uint32 gs = 0;
    if (active && w == 0) gs = hq[(size_t)node * 64 + lane];

    f32x2 accA = {0.f, 0.f}, accB = {0.f, 0.f};

#define EDGE(Q, G, ACC) {                                                     \
        f32x2 e = eb;                                                         \
        e += bflo((uint32)(Q).y) * w0;                                        \
        e += bfhi((uint32)(Q).y) * w1;                                        \
        e += bflo((uint32)(Q).z) * w2;                                        \
        e += bfhi((uint32)(Q).z) * w3;                                        \
        f32x2 m = {bflo(G) + e.x, bfhi(G) + e.y};                             \
        ACC.x += fmaxf(m.x, 0.f);                                             \
        ACC.y += fmaxf(m.y, 0.f);                                             \
    }

    int i = lo;
    for (; i + 8 <= hi; i += 8) {
        int4 q0 = adj[i + 0], q1 = adj[i + 1], q2 = adj[i + 2], q3 = adj[i + 3];
        int4 q4 = adj[i + 4], q5 = adj[i + 5], q6 = adj[i + 6], q7 = adj[i + 7];
        uint32 g0 = hq[(size_t)q0.x * 64 + lane];
        uint32 g1 = hq[(size_t)q1.x * 64 + lane];
        uint32 g2 = hq[(size_t)q2.x * 64 + lane];
        uint32 g3 = hq[(size_t)q3.x * 64 + lane];
        uint32 g4 = hq[(size_t)q4.x * 64 + lane];
        uint32 g5 = hq[(size_t)q5.x * 64 + lane];
        uint32 g6 = hq[(size_t)q6.x * 64 + lane];
        uint32 g7 = hq[(size_t)q7.x * 64 + lane];
        EDGE(q0, g0, accA); EDGE(q1, g1, accB);
        EDGE(q2, g2, accA); EDGE(q3, g3, accB);
        EDGE(q4, g4, accA); EDGE(q5, g5, accB);
        EDGE(q6, g6, accA); EDGE(q7, g7, accB);
    }
    for (; i + 4 <= hi; i += 4) {
        int4 q0 = adj[i + 0], q1 = adj[i + 1], q2 = adj[i + 2], q3 = adj[i + 3];
        uint32 g0 = hq[(size_t)q0.x * 64 + lane];
        uint32 g1 = hq[(size_t)q1.x * 64 + lane];
        uint32 g2 = hq[(size_t)q2.x * 64 + lane];
        uint32 g3 = hq[(size_t)q3.x * 64 + lane];
        EDGE(q0, g0, accA); EDGE(q1, g1, accB);
        EDGE(q2, g2, accA); EDGE(q3, g3, accB);
    }
    for (; i < hi; ++i) {
        int4 q = adj[i];
        uint32 g = hq[(size_t)q.x * 64 + lane];
        EDGE(q, g, accA);
    }
#undef EDGE

    f32x2 tot = {accA.x + accB.x, accA.y + accB.y};
    if (w == 1) red[nodeSlot][lane] = make_float2(tot.x, tot.y);
    __syncthreads();
    if (active && w == 0) {
        float2 o = red[nodeSlot][lane];
        const float ep = 1.0f + eps[l];
        float zl = fmaf(ep, bflo(gs), tot.x + o.x);
        float zh = fmaf(ep, bfhi(gs), tot.y + o.y);
        zq[(size_t)node * 64 + lane] = ((uint32)f2bf(zh) << 16) | (uint32)f2bf(zl);
    }
}

// ---------------- MFMA MLP, operand-swapped ----------------
#define T_STRIDE 136   // shorts; 272B rows: 16B-aligned for b128 reads
__global__ __launch_bounds__(256) void mlp_mfma(
        const ushort16* __restrict__ zq,     // [N64][128] bf16
        const ushort16* __restrict__ Wb1t,   // [128 n][128 k] bf16
        const float* __restrict__ b1,
        const ushort16* __restrict__ Wb2t,
        const float* __restrict__ b2,
        ushort16* __restrict__ h_out, int N) {
    __shared__ ushort16 t_lds[64 * T_STRIDE];
    const int tid = threadIdx.x;
    const int w = tid >> 6, lane = tid & 63;
    const int c = lane & 15, g = lane >> 4;
    const int wrow0 = blockIdx.x * 64 + w * 16;   // node-tile base for this wave

    // ---- GEMM1: t^T = W1^T @ z^T ----
    const ushort16* zrow = zq + (size_t)(wrow0 + c) * HDIM + g * 8;
    short8 bf[4];
#pragma unroll
    for (int kk = 0; kk < 4; ++kk)
        bf[kk] = *(const short8*)(zrow + kk * 32);

    f32x4 acc[8];
#pragma unroll
    for (int n = 0; n < 8; ++n) {
        float4 bb = *(const float4*)(b1 + n * 16 + g * 4);
        acc[n] = (f32x4){bb.x, bb.y, bb.z, bb.w};
    }
#pragma unroll
    for (int kk = 0; kk < 4; ++kk) {
#pragma unroll
        for (int n = 0; n < 8; ++n) {
            short8 af = *(const short8*)(Wb1t + (size_t)(n * 16 + c) * HDIM + kk * 32 + g * 8);
            acc[n] = __builtin_amdgcn_mfma_f32_16x16x32_bf16(af, bf[kk], acc[n], 0, 0, 0);
        }
    }
#pragma unroll
    for (int n = 0; n < 8; ++n) {
        ushort4 u;
        u.x = f2bf(fmaxf(acc[n][0], 0.f));
        u.y = f2bf(fmaxf(acc[n][1], 0.f));
        u.z = f2bf(fmaxf(acc[n][2], 0.f));
        u.w = f2bf(fmaxf(acc[n][3], 0.f));
        *(ushort4*)(&t_lds[(w * 16 + c) * T_STRIDE + n * 16 + g * 4]) = u;
    }
    __syncthreads();

    // ---- GEMM2: h^T = W2^T @ t^T ----
    short8 bf2[4];
#pragma unroll
    for (int kk = 0; kk < 4; ++kk)
        bf2[kk] = *(const short8*)(&t_lds[(w * 16 + c) * T_STRIDE + kk * 32 + g * 8]);

    f32x4 acc2[8];
#pragma unroll
    for (int n = 0; n < 8; ++n) {
        float4 bb = *(const float4*)(b2 + n * 16 + g * 4);
        acc2[n] = (f32x4){bb.x, bb.y, bb.z, bb.w};
    }
#pragma unroll
    for (int kk = 0; kk < 4; ++kk) {
#pragma unroll
        for (int n = 0; n < 8; ++n) {
            short8 af = *(const short8*)(Wb2t + (size_t)(n * 16 + c) * HDIM + kk * 32 + g * 8);
            acc2[n] = __builtin_amdgcn_mfma_f32_16x16x32_bf16(af, bf2[kk], acc2[n], 0, 0, 0);
        }
    }
    if (wrow0 + c < N) {
#pragma unroll
        for (int n = 0; n < 8; ++n) {
            ushort4 u;
            u.x = f2bf(fmaxf(acc2[n][0], 0.f));
            u.y = f2bf(fmaxf(acc2[n][1], 0.f));
            u.z = f2bf(fmaxf(acc2[n][2], 0.f));
            u.w = f2bf(fmaxf(acc2[n][3], 0.f));
            *(ushort4*)(h_out + (size_t)(wrow0 + c) * HDIM + n * 16 + g * 4) = u;
        }
    }
}

// ---------------- output projection (reads bf16 h) ----------------
__global__ void out_kernel(const uint32* __restrict__ hq, const float* __restrict__ Wout,
                           const float* __restrict__ bout, float* __restrict__ out, int N) {
    int idx = blockIdx.x * 256 + threadIdx.x;
    int n = idx >> 4, pe = idx & 15;
    if (n >= N) return;
    float acc = bout[pe];
#pragma unroll 8
    for (int k2 = 0; k2 < 64; ++k2) {
        uint32 g = hq[(size_t)n * 64 + k2];
        acc = fmaf(bflo(g), Wout[(2 * k2) * 16 + pe], acc);
        acc = fmaf(bfhi(g), Wout[(2 * k2 + 1) * 16 + pe], acc);
    }
    out[(size_t)n * 16 + pe] = acc;
}

extern "C" void kernel_launch(void* const* d_in, const int* in_sizes, int n_in,
                              void* d_out, int out_size, void* d_ws, size_t ws_size,
                              hipStream_t stream) {
    const int*   x_type     = (const int*)  d_in[0];
    const float* x_feat     = (const float*)d_in[1];
    const int*   edge_index = (const int*)  d_in[2];
    const float* edge_attr  = (const float*)d_in[3];
    const float* type_embed = (const float*)d_in[4];
    const float* featW      = (const float*)d_in[5];
    const float* featb      = (const float*)d_in[6];
    const float* edgeW      = (const float*)d_in[7];
    const float* edgeb      = (const float*)d_in[8];
    const float* W1         = (const float*)d_in[9];
    const float* b1         = (const float*)d_in[10];
    const float* W2         = (const float*)d_in[11];
    const float* b2         = (const float*)d_in[12];
    const float* eps        = (const float*)d_in[13];
    const float* Wout       = (const float*)d_in[14];
    const float* bout       = (const float*)d_in[15];

    const int N = in_sizes[0];
    const int E = in_sizes[2] / 2;
    const int L = in_sizes[13];
    const int N64 = (N + 63) & ~63;     // pad node buffers so MFMA tiles read in-bounds

    const int* srcIdx = edge_index;
    const int* dstIdx = edge_index + E;

    auto align256 = [](size_t x) { return (x + 255) & ~(size_t)255; };
    char* p = (char*)d_ws;
    ushort16* h_buf  = (ushort16*)p;           p += align256((size_t)N64 * HDIM * 2);
    ushort16* z_buf  = (ushort16*)p;           p += align256((size_t)N64 * HDIM * 2);
    int*   deg_p     = (int*)p;                p += align256((size_t)N * CTR_S * 4);
    int*   fill_p    = (int*)p;                p += align256((size_t)N * CTR_S * 4);
    int*   row_ptr   = (int*)p;                p += align256((size_t)(N + 1) * 4);
    int4*  adj       = (int4*)p;               p += align256((size_t)E * 16);
    int*   partials  = (int*)p;                p += align256(512 * 4);
    int*   offsets   = (int*)p;                p += align256(512 * 4);
    ushort16* Wb1t   = (ushort16*)p;           p += align256((size_t)L * HDIM * HDIM * 2);
    ushort16* Wb2t   = (ushort16*)p;           p += align256((size_t)L * HDIM * HDIM * 2);
    (void)ws_size;

    const int nb = (N + 255) / 256;   // 196 <= 256

    hipMemsetAsync(deg_p, 0, (size_t)N * CTR_S * 4, stream);
    count_kernel<<<(E + 255) / 256, 256, 0, stream>>>(dstIdx, deg_p, E);
    partial_kernel<<<nb, 256, 0, stream>>>(deg_p, partials, N);
    scan_partials_kernel<<<1, 256, 0, stream>>>(partials, offsets, nb, row_ptr, N, E);
    scatter_scan_kernel<<<nb, 256, 0, stream>>>(deg_p, offsets, row_ptr, fill_p, N);
    fill_kernel<<<(E + 255) / 256, 256, 0, stream>>>(srcIdx, dstIdx, edge_attr,
                                                     fill_p, adj, E);

    const int wtotal = L * HDIM * HDIM;
    prep_weights<<<(wtotal + 255) / 256, 256, 0, stream>>>(W1, W2, Wb1t, Wb2t, wtotal);

    embed_kernel<<<((size_t)N * HDIM + 255) / 256, 256, 0, stream>>>(
        x_type, x_feat, type_embed, featW, featb, h_buf, N);

    for (int l = 0; l < L; ++l) {
        agg_kernel<<<(N + 1) / 2, 256, 0, stream>>>(
            (const uint32*)h_buf, row_ptr, adj, edgeW, edgeb, eps, l,
            (uint32*)z_buf, N);
        mlp_mfma<<<N64 / 64, 256, 0, stream>>>(
            z_buf, Wb1t + (size_t)l * HDIM * HDIM, b1 + (size_t)l * HDIM,
            Wb2t + (size_t)l * HDIM * HDIM, b2 + (size_t)l * HDIM, h_buf, N);
    }

    out_kernel<<<((size_t)N * 16 + 255) / 256, 256, 0, stream>>>(
        (const uint32*)h_buf, Wout, bout, (float*)d_out, N);
}

// Round 8
// 380.341 us; speedup vs baseline: 1.1534x; 1.1534x over previous
//
#include <hip/hip_runtime.h>
#include <hip/hip_bf16.h>

// ---------------------------------------------------------------------------
// EncoderGNN: 3-layer GINE encoder, N=50000, E=800000, H=128.
// Round 8: revert r7 (2-wave agg + padded counters both lost). agg = round-6
// scalarized 1-wave/node loop, but PERSISTENT: 4096 blocks x 2 waves grid-
// stride over nodes -> edge weights loaded once per wave (not per node),
// no 25k-block launch ramp. MFMA MLP + 16B edge records unchanged.
// ---------------------------------------------------------------------------

#define HDIM 128

typedef unsigned int uint32;
typedef unsigned short ushort16;
typedef __attribute__((ext_vector_type(8))) short short8;
typedef __attribute__((ext_vector_type(4))) float f32x4;
typedef __attribute__((ext_vector_type(2))) float f32x2;

__device__ __forceinline__ ushort16 f2bf(float f) {
    uint32 u = __float_as_uint(f);
    u += 0x7fff + ((u >> 16) & 1);      // round-to-nearest-even
    return (ushort16)(u >> 16);
}
__device__ __forceinline__ float bflo(uint32 g) { return __uint_as_float(g << 16); }
__device__ __forceinline__ float bfhi(uint32 g) { return __uint_as_float(g & 0xffff0000u); }

// ---------------- CSR build ----------------
__global__ void count_kernel(const int* __restrict__ dstIdx, int* __restrict__ deg, int E) {
    int e = blockIdx.x * blockDim.x + threadIdx.x;
    if (e < E) atomicAdd(&deg[dstIdx[e]], 1);
}

__global__ __launch_bounds__(256) void partial_kernel(const int* __restrict__ deg,
                                                      int* __restrict__ partials, int N) {
    __shared__ int red[256];
    int i = blockIdx.x * 256 + threadIdx.x;
    red[threadIdx.x] = (i < N) ? deg[i] : 0;
    __syncthreads();
#pragma unroll
    for (int off = 128; off > 0; off >>= 1) {
        if (threadIdx.x < off) red[threadIdx.x] += red[threadIdx.x + off];
        __syncthreads();
    }
    if (threadIdx.x == 0) partials[blockIdx.x] = red[0];
}

__global__ __launch_bounds__(256) void scan_partials_kernel(const int* __restrict__ partials,
                                                            int* __restrict__ offsets,
                                                            int nb, int* __restrict__ row_ptr,
                                                            int N, int E) {
    __shared__ int buf[256];
    int tid = threadIdx.x;
    buf[tid] = (tid < nb) ? partials[tid] : 0;
    __syncthreads();
#pragma unroll
    for (int off = 1; off < 256; off <<= 1) {
        int v = (tid >= off) ? buf[tid - off] : 0;
        __syncthreads();
        buf[tid] += v;
        __syncthreads();
    }
    if (tid < nb) offsets[tid] = buf[tid] - partials[tid];   // exclusive
    if (tid == 0) row_ptr[N] = E;
}

__global__ __launch_bounds__(256) void scatter_scan_kernel(const int* __restrict__ deg,
                                                           const int* __restrict__ offsets,
                                                           int* __restrict__ row_ptr,
                                                           int* __restrict__ fill_ptr, int N) {
    __shared__ int buf[256];
    int tid = threadIdx.x;
    int i = blockIdx.x * 256 + tid;
    int v = (i < N) ? deg[i] : 0;
    buf[tid] = v;
    __syncthreads();
#pragma unroll
    for (int off = 1; off < 256; off <<= 1) {
        int t = (tid >= off) ? buf[tid - off] : 0;
        __syncthreads();
        buf[tid] += t;
        __syncthreads();
    }
    if (i < N) {
        int excl = buf[tid] - v + offsets[blockIdx.x];
        row_ptr[i]  = excl;
        fill_ptr[i] = excl;
    }
}

// one 16B record per edge: {src, ea01(bf16x2), ea23(bf16x2), 0}
__global__ void fill_kernel(const int* __restrict__ srcIdx, const int* __restrict__ dstIdx,
                            const float* __restrict__ edge_attr,
                            int* __restrict__ fill_ptr, int4* __restrict__ adj, int E) {
    int e = blockIdx.x * blockDim.x + threadIdx.x;
    if (e < E) {
        int d = dstIdx[e];
        int pos = atomicAdd(&fill_ptr[d], 1);
        float4 ea = *(const float4*)(edge_attr + (size_t)e * 4);
        int4 rec;
        rec.x = srcIdx[e];
        rec.y = (int)(((uint32)f2bf(ea.y) << 16) | (uint32)f2bf(ea.x));
        rec.z = (int)(((uint32)f2bf(ea.w) << 16) | (uint32)f2bf(ea.z));
        rec.w = 0;
        adj[pos] = rec;
    }
}

// ---------------- weight prep: bf16 + transpose (once per call) ----------------
__global__ void prep_weights(const float* __restrict__ W1, const float* __restrict__ W2,
                             ushort16* __restrict__ Wb1t, ushort16* __restrict__ Wb2t, int total) {
    int idx = blockIdx.x * 256 + threadIdx.x;
    if (idx >= total) return;
    int l = idx >> 14;
    int rem = idx & 16383;
    int n = rem >> 7, k = rem & 127;
    size_t src = (size_t)l * 16384 + (size_t)k * 128 + n;
    size_t dst = (size_t)l * 16384 + (size_t)n * 128 + k;
    Wb1t[dst] = f2bf(W1[src]);
    Wb2t[dst] = f2bf(W2[src]);
}

// ---------------- node embedding (writes bf16 h) ----------------
__global__ void embed_kernel(const int* __restrict__ x_type, const float* __restrict__ x_feat,
                             const float* __restrict__ type_embed, const float* __restrict__ featW,
                             const float* __restrict__ featb, ushort16* __restrict__ h, int N) {
    int idx = blockIdx.x * 256 + threadIdx.x;
    int n = idx >> 7, c = idx & 127;
    if (n >= N) return;
    int t = x_type[n];
    float acc = type_embed[(size_t)t * HDIM + c] + featb[c];
#pragma unroll
    for (int k = 0; k < 7; ++k)
        acc = fmaf(x_feat[(size_t)n * 7 + k], featW[(size_t)k * HDIM + c], acc);
    h[(size_t)n * HDIM + c] = f2bf(acc);
}

// ---------------- aggregation: persistent waves, grid-stride over nodes ----------------
// 1 wave per node per stride step; edge loop wave-uniform (scalarized bounds);
// weights loaded ONCE per wave and reused across ~N/8192 nodes.
__global__ __launch_bounds__(128) void agg_kernel(
        const uint32* __restrict__ hq,       // [N][64] packed bf16x2
        const int* __restrict__ row_ptr,
        const int4* __restrict__ adj,        // 16B records (uniform per wave)
        const float* __restrict__ edgeW, const float* __restrict__ edgeb,
        const float* __restrict__ eps, int l, uint32* __restrict__ zq, int N) {
    const int lane = threadIdx.x & 63;
    const int wid  = blockIdx.x * 2 + (threadIdx.x >> 6);
    const int nw   = gridDim.x * 2;

    const int c0 = 2 * lane;
    const f32x2 w0 = {edgeW[c0],       edgeW[c0 + 1]};
    const f32x2 w1 = {edgeW[128 + c0], edgeW[128 + c0 + 1]};
    const f32x2 w2 = {edgeW[256 + c0], edgeW[256 + c0 + 1]};
    const f32x2 w3 = {edgeW[384 + c0], edgeW[384 + c0 + 1]};
    const f32x2 eb = {edgeb[c0],       edgeb[c0 + 1]};
    const float ep = 1.0f + eps[l];

#define EDGE(Q, G, ACC) {                                                     \
        f32x2 e = eb;                                                         \
        e += bflo((uint32)(Q).y) * w0;                                        \
        e += bfhi((uint32)(Q).y) * w1;                                        \
        e += bflo((uint32)(Q).z) * w2;                                        \
        e += bfhi((uint32)(Q).z) * w3;                                        \
        f32x2 m = {bflo(G) + e.x, bfhi(G) + e.y};                             \
        ACC.x += fmaxf(m.x, 0.f);                                             \
        ACC.y += fmaxf(m.y, 0.f);                                             \
    }

    for (int node = wid; node < N; node += nw) {
        const int beg = __builtin_amdgcn_readfirstlane(row_ptr[node]);
        const int end = __builtin_amdgcn_readfirstlane(row_ptr[node + 1]);
        const uint32 gs = hq[(size_t)node * 64 + lane];   // self-term early

        f32x2 accA = {0.f, 0.f}, accB = {0.f, 0.f};
        int i = beg;
        for (; i + 8 <= end; i += 8) {
            int4 q0 = adj[i + 0], q1 = adj[i + 1], q2 = adj[i + 2], q3 = adj[i + 3];
            int4 q4 = adj[i + 4], q5 = adj[i + 5], q6 = adj[i + 6], q7 = adj[i + 7];
            uint32 g0 = hq[(size_t)q0.x * 64 + lane];
            uint32 g1 = hq[(size_t)q1.x * 64 + lane];
            uint32 g2 = hq[(size_t)q2.x * 64 + lane];
            uint32 g3 = hq[(size_t)q3.x * 64 + lane];
            uint32 g4 = hq[(size_t)q4.x * 64 + lane];
            uint32 g5 = hq[(size_t)q5.x * 64 + lane];
            uint32 g6 = hq[(size_t)q6.x * 64 + lane];
            uint32 g7 = hq[(size_t)q7.x * 64 + lane];
            EDGE(q0, g0, accA); EDGE(q1, g1, accB);
            EDGE(q2, g2, accA); EDGE(q3, g3, accB);
            EDGE(q4, g4, accA); EDGE(q5, g5, accB);
            EDGE(q6, g6, accA); EDGE(q7, g7, accB);
        }
        for (; i + 4 <= end; i += 4) {
            int4 q0 = adj[i + 0], q1 = adj[i + 1], q2 = adj[i + 2], q3 = adj[i + 3];
            uint32 g0 = hq[(size_t)q0.x * 64 + lane];
            uint32 g1 = hq[(size_t)q1.x * 64 + lane];
            uint32 g2 = hq[(size_t)q2.x * 64 + lane];
            uint32 g3 = hq[(size_t)q3.x * 64 + lane];
            EDGE(q0, g0, accA); EDGE(q1, g1, accB);
            EDGE(q2, g2, accA); EDGE(q3, g3, accB);
        }
        for (; i < end; ++i) {
            int4 q = adj[i];
            uint32 g = hq[(size_t)q.x * 64 + lane];
            EDGE(q, g, accA);
        }

        float zl = fmaf(ep, bflo(gs), accA.x + accB.x);
        float zh = fmaf(ep, bfhi(gs), accA.y + accB.y);
        zq[(size_t)node * 64 + lane] = ((uint32)f2bf(zh) << 16) | (uint32)f2bf(zl);
    }
#undef EDGE
}

// ---------------- MFMA MLP, operand-swapped ----------------
#define T_STRIDE 136   // shorts; 272B rows: 16B-aligned for b128 reads
__global__ __launch_bounds__(256) void mlp_mfma(
        const ushort16* __restrict__ zq,     // [N64][128] bf16
        const ushort16* __restrict__ Wb1t,   // [128 n][128 k] bf16
        const float* __restrict__ b1,
        const ushort16* __restrict__ Wb2t,
        const float* __restrict__ b2,
        ushort16* __restrict__ h_out, int N) {
    __shared__ ushort16 t_lds[64 * T_STRIDE];
    const int tid = threadIdx.x;
    const int w = tid >> 6, lane = tid & 63;
    const int c = lane & 15, g = lane >> 4;
    const int wrow0 = blockIdx.x * 64 + w * 16;   // node-tile base for this wave

    // ---- GEMM1: t^T = W1^T @ z^T ----
    const ushort16* zrow = zq + (size_t)(wrow0 + c) * HDIM + g * 8;
    short8 bf[4];
#pragma unroll
    for (int kk = 0; kk < 4; ++kk)
        bf[kk] = *(const short8*)(zrow + kk * 32);

    f32x4 acc[8];
#pragma unroll
    for (int n = 0; n < 8; ++n) {
        float4 bb = *(const float4*)(b1 + n * 16 + g * 4);
        acc[n] = (f32x4){bb.x, bb.y, bb.z, bb.w};
    }
#pragma unroll
    for (int kk = 0; kk < 4; ++kk) {
#pragma unroll
        for (int n = 0; n < 8; ++n) {
            short8 af = *(const short8*)(Wb1t + (size_t)(n * 16 + c) * HDIM + kk * 32 + g * 8);
            acc[n] = __builtin_amdgcn_mfma_f32_16x16x32_bf16(af, bf[kk], acc[n], 0, 0, 0);
        }
    }
#pragma unroll
    for (int n = 0; n < 8; ++n) {
        ushort4 u;
        u.x = f2bf(fmaxf(acc[n][0], 0.f));
        u.y = f2bf(fmaxf(acc[n][1], 0.f));
        u.z = f2bf(fmaxf(acc[n][2], 0.f));
        u.w = f2bf(fmaxf(acc[n][3], 0.f));
        *(ushort4*)(&t_lds[(w * 16 + c) * T_STRIDE + n * 16 + g * 4]) = u;
    }
    __syncthreads();

    // ---- GEMM2: h^T = W2^T @ t^T ----
    short8 bf2[4];
#pragma unroll
    for (int kk = 0; kk < 4; ++kk)
        bf2[kk] = *(const short8*)(&t_lds[(w * 16 + c) * T_STRIDE + kk * 32 + g * 8]);

    f32x4 acc2[8];
#pragma unroll
    for (int n = 0; n < 8; ++n) {
        float4 bb = *(const float4*)(b2 + n * 16 + g * 4);
        acc2[n] = (f32x4){bb.x, bb.y, bb.z, bb.w};
    }
#pragma unroll
    for (int kk = 0; kk < 4; ++kk) {
#pragma unroll
        for (int n = 0; n < 8; ++n) {
            short8 af = *(const short8*)(Wb2t + (size_t)(n * 16 + c) * HDIM + kk * 32 + g * 8);
            acc2[n] = __builtin_amdgcn_mfma_f32_16x16x32_bf16(af, bf2[kk], acc2[n], 0, 0, 0);
        }
    }
    if (wrow0 + c < N) {
#pragma unroll
        for (int n = 0; n < 8; ++n) {
            ushort4 u;
            u.x = f2bf(fmaxf(acc2[n][0], 0.f));
            u.y = f2bf(fmaxf(acc2[n][1], 0.f));
            u.z = f2bf(fmaxf(acc2[n][2], 0.f));
            u.w = f2bf(fmaxf(acc2[n][3], 0.f));
            *(ushort4*)(h_out + (size_t)(wrow0 + c) * HDIM + n * 16 + g * 4) = u;
        }
    }
}

// ---------------- output projection (reads bf16 h) ----------------
__global__ void out_kernel(const uint32* __restrict__ hq, const float* __restrict__ Wout,
                           const float* __restrict__ bout, float* __restrict__ out, int N) {
    int idx = blockIdx.x * 256 + threadIdx.x;
    int n = idx >> 4, pe = idx & 15;
    if (n >= N) return;
    float acc = bout[pe];
#pragma unroll 8
    for (int k2 = 0; k2 < 64; ++k2) {
        uint32 g = hq[(size_t)n * 64 + k2];
        acc = fmaf(bflo(g), Wout[(2 * k2) * 16 + pe], acc);
        acc = fmaf(bfhi(g), Wout[(2 * k2 + 1) * 16 + pe], acc);
    }
    out[(size_t)n * 16 + pe] = acc;
}

extern "C" void kernel_launch(void* const* d_in, const int* in_sizes, int n_in,
                              void* d_out, int out_size, void* d_ws, size_t ws_size,
                              hipStream_t stream) {
    const int*   x_type     = (const int*)  d_in[0];
    const float* x_feat     = (const float*)d_in[1];
    const int*   edge_index = (const int*)  d_in[2];
    const float* edge_attr  = (const float*)d_in[3];
    const float* type_embed = (const float*)d_in[4];
    const float* featW      = (const float*)d_in[5];
    const float* featb      = (const float*)d_in[6];
    const float* edgeW      = (const float*)d_in[7];
    const float* edgeb      = (const float*)d_in[8];
    const float* W1         = (const float*)d_in[9];
    const float* b1         = (const float*)d_in[10];
    const float* W2         = (const float*)d_in[11];
    const float* b2         = (const float*)d_in[12];
    const float* eps        = (const float*)d_in[13];
    const float* Wout       = (const float*)d_in[14];
    const float* bout       = (const float*)d_in[15];

    const int N = in_sizes[0];
    const int E = in_sizes[2] / 2;
    const int L = in_sizes[13];
    const int N64 = (N + 63) & ~63;     // pad node buffers so MFMA tiles read in-bounds

    const int* srcIdx = edge_index;
    const int* dstIdx = edge_index + E;

    auto align256 = [](size_t x) { return (x + 255) & ~(size_t)255; };
    char* p = (char*)d_ws;
    ushort16* h_buf  = (ushort16*)p;           p += align256((size_t)N64 * HDIM * 2);
    ushort16* z_buf  = (ushort16*)p;           p += align256((size_t)N64 * HDIM * 2);
    int*   deg       = (int*)p;                p += align256((size_t)N * 4);
    int*   row_ptr   = (int*)p;                p += align256((size_t)(N + 1) * 4);
    int*   fill_ptr  = (int*)p;                p += align256((size_t)N * 4);
    int4*  adj       = (int4*)p;               p += align256((size_t)E * 16);
    int*   partials  = (int*)p;                p += align256(512 * 4);
    int*   offsets   = (int*)p;                p += align256(512 * 4);
    ushort16* Wb1t   = (ushort16*)p;           p += align256((size_t)L * HDIM * HDIM * 2);
    ushort16* Wb2t   = (ushort16*)p;           p += align256((size_t)L * HDIM * HDIM * 2);
    (void)ws_size;

    const int nb = (N + 255) / 256;   // 196 <= 256

    hipMemsetAsync(deg, 0, (size_t)N * 4, stream);
    count_kernel<<<(E + 255) / 256, 256, 0, stream>>>(dstIdx, deg, E);
    partial_kernel<<<nb, 256, 0, stream>>>(deg, partials, N);
    scan_partials_kernel<<<1, 256, 0, stream>>>(partials, offsets, nb, row_ptr, N, E);
    scatter_scan_kernel<<<nb, 256, 0, stream>>>(deg, offsets, row_ptr, fill_ptr, N);
    fill_kernel<<<(E + 255) / 256, 256, 0, stream>>>(srcIdx, dstIdx, edge_attr,
                                                     fill_ptr, adj, E);

    const int wtotal = L * HDIM * HDIM;
    prep_weights<<<(wtotal + 255) / 256, 256, 0, stream>>>(W1, W2, Wb1t, Wb2t, wtotal);

    embed_kernel<<<((size_t)N * HDIM + 255) / 256, 256, 0, stream>>>(
        x_type, x_feat, type_embed, featW, featb, h_buf, N);

    for (int l = 0; l < L; ++l) {
        agg_kernel<<<4096, 128, 0, stream>>>(
            (const uint32*)h_buf, row_ptr, adj, edgeW, edgeb, eps, l,
            (uint32*)z_buf, N);
        mlp_mfma<<<N64 / 64, 256, 0, stream>>>(
            z_buf, Wb1t + (size_t)l * HDIM * HDIM, b1 + (size_t)l * HDIM,
            Wb2t + (size_t)l * HDIM * HDIM, b2 + (size_t)l * HDIM, h_buf, N);
    }

    out_kernel<<<((size_t)N * 16 + 255) / 256, 256, 0, stream>>>(
        (const uint32*)h_buf, Wout, bout, (float*)d_out, N);
}